// Round 3
// baseline (83.500 us; speedup 1.0000x reference)
//
#include <hip/hip_runtime.h>

// Problem constants (match reference setup)
#define BB     4
#define NW     128
#define HG     512
#define WG     512
#define EDIM   64
#define HIDDEN 768
#define CT_STRIDE 132

typedef float f4 __attribute__((ext_vector_type(4)));

// d_ws layout (bytes):
//   ctabT : [BB][EDIM][CT_STRIDE] f32  @ 0        (135,168 B)
//   winner: [BB][HG][WG] u8            @ 139,264  (1,048,576 B)
#define WS_CTABT  0
#define WS_WINNER 139264

// ---------------------------------------------------------------------------
// Kernel A: blocks 0..131  -> compact projected table ctabT[b][e][n]
//           blocks 132..387 -> max-priority winner raster (u8 map)
// ---------------------------------------------------------------------------
__global__ __launch_bounds__(256) void prep_kernel(
    const float* __restrict__ bbox,
    const float* __restrict__ emb,
    const float* __restrict__ proj,
    const int*   __restrict__ ids,
    const int*   __restrict__ stride_p,
    float*         __restrict__ ctabT,
    unsigned char* __restrict__ winner)
{
    const int t  = threadIdx.x;
    const int bx = blockIdx.x;

    if (bx < 132) {
        // ---- ctab: 4 n-values per block, LDS-staged proj K-tiles ----
        __shared__ float proj_s[64][65];   // pad -> (e+k)%32 banks, 2-way free
        __shared__ float emb_s[4][65];

        const int b  = bx / 33;
        const int ng = bx % 33;
        const int e  = t & 63;
        const int r  = t >> 6;             // wave index = n-row
        const int n  = ng * 4 + r;         // 0..131
        const bool valid = (n <= NW);
        const int id = (!valid || n == 0) ? 0 : ids[b * NW + n - 1];
        const float* erow = emb + (size_t)id * HIDDEN;

        float acc = 0.f;
        for (int kt = 0; kt < HIDDEN; kt += 64) {
            emb_s[r][e] = erow[kt + e];                       // coalesced 256B/wave
            #pragma unroll
            for (int idx = t; idx < 64 * 64; idx += 256) {    // 16 iters
                proj_s[idx >> 6][idx & 63] =
                    proj[(size_t)(idx >> 6) * HIDDEN + kt + (idx & 63)];
            }
            __syncthreads();
            #pragma unroll 16
            for (int k = 0; k < 64; ++k)
                acc += emb_s[r][k] * proj_s[e][k];            // bcast + 2-way
            __syncthreads();
        }
        if (valid) ctabT[((size_t)(b * EDIM + e)) * CT_STRIDE + n] = acc;
        return;
    }

    // ---- winner raster: one block per (b, 8-row tile) ----
    const int wb    = bx - 132;            // 0..255
    const int b     = wb >> 6;
    const int hbase = (wb & 63) * 8;
    const float s = (float)stride_p[0];

    __shared__ int fw0[NW], fw1[NW], fh0[NW], fh1[NW], fpr[NW];
    __shared__ int cnt;
    if (t == 0) cnt = 0;
    __syncthreads();

    if (t < NW) {
        float4 bv = ((const float4*)bbox)[b * NW + t];
        int w0 = (int)rintf(bv.x / s);
        int h0 = (int)rintf(bv.y / s);
        int w1 = (int)rintf(bv.z / s);
        int h1 = (int)rintf(bv.w / s);
        if (h1 > hbase && h0 < hbase + 8) {
            int i = atomicAdd(&cnt, 1);
            fw0[i] = w0; fw1[i] = w1; fh0[i] = h0; fh1[i] = h1; fpr[i] = t + 1;
        }
    }
    __syncthreads();

    const int nc  = cnt;
    const int q   = t & 127;
    const int w0p = q * 4;
    for (int rr = 0; rr < 4; ++rr) {
        const int row = hbase + rr * 2 + (t >> 7);
        int wn0 = 0, wn1 = 0, wn2 = 0, wn3 = 0;
        for (int i = 0; i < nc; ++i) {
            if (row >= fh0[i] && row < fh1[i]) {
                int a = fw0[i], z = fw1[i], p = fpr[i];
                if (w0p     >= a && w0p     < z) wn0 = max(wn0, p);
                if (w0p + 1 >= a && w0p + 1 < z) wn1 = max(wn1, p);
                if (w0p + 2 >= a && w0p + 2 < z) wn2 = max(wn2, p);
                if (w0p + 3 >= a && w0p + 3 < z) wn3 = max(wn3, p);
            }
        }
        uchar4 u;
        u.x = (unsigned char)wn0; u.y = (unsigned char)wn1;
        u.z = (unsigned char)wn2; u.w = (unsigned char)wn3;
        *(uchar4*)(winner + ((size_t)(b * HG + row)) * WG + w0p) = u;
    }
}

// ---------------------------------------------------------------------------
// Kernel B: paint. One block per (b, e, 256-row half-plane): one contiguous
// 512 KB nontemporal write stream per block. 129-float column in LDS.
// ---------------------------------------------------------------------------
__global__ __launch_bounds__(256) void paint_kernel(
    const float*         __restrict__ ctabT,
    const unsigned char* __restrict__ winner,
    float*               __restrict__ out)
{
    const int t  = threadIdx.x;
    const int hh = blockIdx.x;   // 0..1
    const int e  = blockIdx.y;   // 0..63
    const int b  = blockIdx.z;   // 0..3

    __shared__ float col[CT_STRIDE];
    if (t < CT_STRIDE)
        col[t] = (t <= NW) ? ctabT[((size_t)(b * EDIM + e)) * CT_STRIDE + t] : 0.f;
    __syncthreads();

    const uchar4* wrow = (const uchar4*)(winner + ((size_t)(b * HG + hh * 256)) * WG);
    f4* obase = (f4*)(out + ((size_t)((b * EDIM + e) * HG) + hh * 256) * WG);

    #pragma unroll 8
    for (int i = 0; i < 128; ++i) {
        const int qq = i * 256 + t;          // 32768 quads = 512 KB
        uchar4 wn = wrow[qq];
        f4 v;
        v.x = col[wn.x];
        v.y = col[wn.y];
        v.z = col[wn.z];
        v.w = col[wn.w];
        __builtin_nontemporal_store(v, obase + qq);
    }
}

// ---------------------------------------------------------------------------
extern "C" void kernel_launch(void* const* d_in, const int* in_sizes, int n_in,
                              void* d_out, int out_size, void* d_ws, size_t ws_size,
                              hipStream_t stream)
{
    // inputs: 0 img (unused), 1 bbox, 2 emb_weight, 3 proj_weight,
    //         4 input_ids, 5 stride
    const float* bbox = (const float*)d_in[1];
    const float* emb  = (const float*)d_in[2];
    const float* proj = (const float*)d_in[3];
    const int*   ids  = (const int*)d_in[4];
    const int*   strd = (const int*)d_in[5];

    float* out = (float*)d_out;
    char*  ws  = (char*)d_ws;
    float*         ctabT  = (float*)(ws + WS_CTABT);
    unsigned char* winner = (unsigned char*)(ws + WS_WINNER);

    prep_kernel<<<132 + BB * (HG / 8), 256, 0, stream>>>(
        bbox, emb, proj, ids, strd, ctabT, winner);

    dim3 g2(2, EDIM, BB);
    paint_kernel<<<g2, 256, 0, stream>>>(ctabT, winner, out);
}